// Round 4
// baseline (103.432 us; speedup 1.0000x reference)
//
#include <hip/hip_runtime.h>
#include <math.h>

// N = 2^22, 22 stages of real-butterfly + magnitude (|.| after every stage —
// stage order fixed, NOT commutable like a true FFT).
// Stage s (m=2^s) pairs (p, p+m/2), twiddle fraction r = (p mod m/2)/m revolutions:
//   out_e = sqrt((e + c*o)^2 + (s*o)^2), out_o = sqrt((e - c*o)^2 + (s*o)^2).
//
// P: tiled bitrev permute (64x65 LDS tile, coalesced both sides) + stages 1-3
//    (constant twiddles: abs / hypot / +-sqrt2/2 forms — near zero trans ops)
// A: stages 4-13 in contiguous 8192-chunks; radix-8 register groups; ALL twiddles
//    per group from ONE sincos via exact double-angle + octant rotations.
// B: stages 14-22 over 512-elem stride-8192 combs; same twiddle scheme.
//
// v_sin/v_cos take REVOLUTIONS. Lean registers -> (1024,8): 2 blocks/CU = 32 waves.

#define NBITS 22
#define RSQ2 0.70710678118654752440f

__device__ __forceinline__ float hsqrt(float x) { return __builtin_amdgcn_sqrtf(x); }

__device__ __forceinline__ void bf(float& e, float& o, float c, float s) {
    float rp = fmaf(c, o, e);
    float rm = fmaf(-c, o, e);
    float im = s * o;
    float im2 = im * im;
    e = hsqrt(fmaf(rp, rp, im2));
    o = hsqrt(fmaf(rm, rm, im2));
}
__device__ __forceinline__ void bf0(float& e, float& o) {   // twiddle (1,0): k=0
    float a = e + o, b = e - o;
    e = fabsf(a); o = fabsf(b);
}
__device__ __forceinline__ void bfq(float& e, float& o) {   // twiddle (0,1): k=m/4
    float h = hsqrt(fmaf(e, e, o * o));
    e = h; o = h;
}

// 3 radix-2 stages on 8 regs. (c2,s2) = cos/sin(2*pi*b2) for the LAST sub-stage's
// base fraction b2; b1 = 2*b2, b0 = 4*b2 derived exactly by double-angle.
// Offsets: +0.25 rev -> (c,s)->(-s,c) free; +0.125 -> rotate by sqrt2/2.
__device__ __forceinline__ void radix8f(float v[8], float c2, float s2) {
    float c1 = fmaf(-2.f * s2, s2, 1.f);
    float s1 = 2.f * s2 * c2;
    float c0 = fmaf(-2.f * s1, s1, 1.f);
    float s0 = 2.f * s1 * c1;
    bf(v[0], v[1], c0, s0); bf(v[2], v[3], c0, s0);
    bf(v[4], v[5], c0, s0); bf(v[6], v[7], c0, s0);
    bf(v[0], v[2], c1, s1); bf(v[4], v[6], c1, s1);
    bf(v[1], v[3], -s1, c1); bf(v[5], v[7], -s1, c1);       // b1 + 0.25
    bf(v[0], v[4], c2, s2);
    float u = RSQ2 * (c2 - s2), w = RSQ2 * (c2 + s2);
    bf(v[1], v[5], u, w);                                   // b2 + 0.125
    bf(v[2], v[6], -s2, c2);                                // b2 + 0.25
    bf(v[3], v[7], -w, u);                                  // b2 + 0.375
}

// stages 1..3: all twiddles constant (0, 1/4, 1/8, 3/8 rev)
__device__ __forceinline__ void radix8z(float v[8]) {
    bf0(v[0], v[1]); bf0(v[2], v[3]); bf0(v[4], v[5]); bf0(v[6], v[7]);
    bf0(v[0], v[2]); bf0(v[4], v[6]);
    bfq(v[1], v[3]); bfq(v[5], v[7]);
    bf0(v[0], v[4]);
    bf(v[1], v[5], RSQ2, RSQ2);
    bfq(v[2], v[6]);
    bf(v[3], v[7], -RSQ2, RSQ2);
}

// pad: +4 floats per 32 -> stride-{8,64,512} combs stay <=2-way; 8-runs stay
// contiguous and 16B-aligned (b128-able).
#define PAD32(i) ((i) + (((i) >> 5) << 2))

// ---------------- Kernel P: bitrev permute + stages 1..3 ----------------
// p = hi11*2048 + lo11; brev22(p) = brev11(lo11)*2048 + brev11(hi11).
__global__ __launch_bounds__(256, 8) void fft_perm(const float* __restrict__ x,
                                                   float* __restrict__ y) {
    __shared__ float lds[64 * 65];
    const unsigned tid = threadIdx.x;
    const unsigned tx = tid & 63, g = tid >> 6;
    const unsigned C0 = (blockIdx.x & 31) * 64;
    const unsigned B0 = (blockIdx.x >> 5) * 64;

#pragma unroll
    for (int k = 0; k < 16; ++k) {
        unsigned r = g * 16 + k;
        unsigned a = __brev(C0 + r) >> (32 - 11);
        lds[r * 65 + tx] = x[a * 2048u + B0 + tx];
    }
    __syncthreads();

    float v[8];
#pragma unroll
    for (int q = 0; q < 2; ++q) {
        unsigned task = tid + 256u * q;
        unsigned c = task >> 3, grp = task & 7;
#pragma unroll
        for (int j = 0; j < 8; ++j) v[j] = lds[(grp * 8 + j) * 65 + c];
        radix8z(v);                                   // stages 1..3
        unsigned pr = __brev(B0 + c) >> (32 - 11);
        float* dst = y + pr * 2048u + C0 + grp * 8;
        *(float4*)(dst)     = make_float4(v[0], v[1], v[2], v[3]);
        *(float4*)(dst + 4) = make_float4(v[4], v[5], v[6], v[7]);
    }
}

// ---------------- Kernel A: stages 4..13 ----------------
__global__ __launch_bounds__(1024, 8) void fft_low(float* __restrict__ y) {
    __shared__ float lds[9216];
    const unsigned t = threadIdx.x;
    const unsigned base = blockIdx.x * 8192;
    float v[8];

    {   // contiguous load -> contiguous aligned LDS write (b128)
        const float4* src = (const float4*)(y + base + t * 8);
        float4 u0 = src[0], u1 = src[1];
        float* dst = &lds[PAD32(t * 8)];
        ((float4*)dst)[0] = u0;
        ((float4*)dst)[1] = u1;
    }
    __syncthreads();

    // stages 4..6 (h=8): idx = hi*64 + j*8 + lo, b2 = lo/64
    {
        const unsigned lo = t & 7, hi = t >> 3;
        const unsigned i0 = hi * 64 + lo;
#pragma unroll
        for (int j = 0; j < 8; ++j) v[j] = lds[PAD32(i0 + j * 8)];
        float r = (float)lo * (1.f / 64);
        radix8f(v, __builtin_amdgcn_cosf(r), __builtin_amdgcn_sinf(r));
#pragma unroll
        for (int j = 0; j < 8; ++j) lds[PAD32(i0 + j * 8)] = v[j];
    }
    __syncthreads();

    // stages 7..9 (h=64): idx = hi*512 + j*64 + lo, b2 = lo/512
    {
        const unsigned lo = t & 63, hi = t >> 6;
        const unsigned i0 = hi * 512 + lo;
#pragma unroll
        for (int j = 0; j < 8; ++j) v[j] = lds[PAD32(i0 + j * 64)];
        float r = (float)lo * (1.f / 512);
        radix8f(v, __builtin_amdgcn_cosf(r), __builtin_amdgcn_sinf(r));
#pragma unroll
        for (int j = 0; j < 8; ++j) lds[PAD32(i0 + j * 64)] = v[j];
    }
    __syncthreads();

    // stages 10..12 (h=512): idx = hi*4096 + j*512 + lo, b2 = lo/4096
    {
        const unsigned lo = t & 511, hi = t >> 9;
        const unsigned i0 = hi * 4096 + lo;
#pragma unroll
        for (int j = 0; j < 8; ++j) v[j] = lds[PAD32(i0 + j * 512)];
        float r = (float)lo * (1.f / 4096);
        radix8f(v, __builtin_amdgcn_cosf(r), __builtin_amdgcn_sinf(r));
#pragma unroll
        for (int j = 0; j < 8; ++j) lds[PAD32(i0 + j * 512)] = v[j];
    }
    __syncthreads();

    // stage 13 (pairs i, i+4096; r = i/8192 = t/8192 + it/8):
    // one sincos + pi/4 rotation per iteration.
    {
        float c = __builtin_amdgcn_cosf((float)t * (1.f / 8192));
        float s = __builtin_amdgcn_sinf((float)t * (1.f / 8192));
#pragma unroll
        for (int it = 0; it < 4; ++it) {
            const unsigned i = it * 1024 + t;
            float e = lds[PAD32(i)];
            float o = lds[PAD32(i + 4096)];
            bf(e, o, c, s);
            y[base + i] = e;
            y[base + i + 4096] = o;
            float nc = RSQ2 * (c - s);
            s = RSQ2 * (c + s);
            c = nc;
        }
    }
}

// ---------------- Kernel B: stages 14..22 ----------------
__global__ __launch_bounds__(1024, 8) void fft_high(float* __restrict__ y) {
    __shared__ float lds[512 * 17 + 16];          // [t][li] row stride 17
    const unsigned tt = threadIdx.x;
    const unsigned li = tt & 15, u = tt >> 4;     // u = 0..63
    const unsigned low = blockIdx.x * 16 + li;
    float v[8];

    // stages 14..16 (t-stride 1): b2 = low/65536
#pragma unroll
    for (int j = 0; j < 8; ++j) v[j] = y[low + 8192u * (u * 8 + j)];
    {
        float r = (float)low * (1.f / 65536);
        radix8f(v, __builtin_amdgcn_cosf(r), __builtin_amdgcn_sinf(r));
    }
#pragma unroll
    for (int j = 0; j < 8; ++j) lds[(u * 8 + j) * 17 + li] = v[j];
    __syncthreads();

    // stages 17..19 (t-stride 8): b2 = (low + 8192*lo8)/524288
    {
        const unsigned lo8 = u & 7, hi = u >> 3;
        const unsigned t0 = hi * 64 + lo8;
#pragma unroll
        for (int j = 0; j < 8; ++j) v[j] = lds[(t0 + j * 8) * 17 + li];
        float r = ((float)low + 8192.f * (float)lo8) * (1.f / 524288);
        radix8f(v, __builtin_amdgcn_cosf(r), __builtin_amdgcn_sinf(r));
#pragma unroll
        for (int j = 0; j < 8; ++j) lds[(t0 + j * 8) * 17 + li] = v[j];
    }
    __syncthreads();

    // stages 20..22 (t-stride 64): b2 = (low + 8192*u)/4194304
    {
#pragma unroll
        for (int j = 0; j < 8; ++j) v[j] = lds[(u + j * 64) * 17 + li];
        float r = ((float)low + 8192.f * (float)u) * (1.f / 4194304);
        radix8f(v, __builtin_amdgcn_cosf(r), __builtin_amdgcn_sinf(r));
#pragma unroll
        for (int j = 0; j < 8; ++j) y[low + 8192u * (u + j * 64)] = v[j];
    }
}

extern "C" void kernel_launch(void* const* d_in, const int* in_sizes, int n_in,
                              void* d_out, int out_size, void* d_ws, size_t ws_size,
                              hipStream_t stream) {
    const float* x = (const float*)d_in[0];
    float* out = (float*)d_out;

    fft_perm<<<dim3(1024), dim3(256), 0, stream>>>(x, out);
    fft_low<<<dim3(512), dim3(1024), 0, stream>>>(out);
    fft_high<<<dim3(512), dim3(1024), 0, stream>>>(out);
}

// Round 5
// 100.980 us; speedup vs baseline: 1.0243x; 1.0243x over previous
//
#include <hip/hip_runtime.h>
#include <math.h>

// N = 2^22, 22 stages of real-butterfly + magnitude (|.| after every stage —
// stage order fixed, NOT commutable like a true FFT).
// Stage s (m=2^s) pairs (p, p+m/2), twiddle fraction r = (p mod m/2)/m revolutions:
//   out_e = sqrt((e + c*o)^2 + (s*o)^2), out_o = sqrt((e - c*o)^2 + (s*o)^2).
//
// P: tiled bitrev permute (64x65 LDS tile) + stages 1-3 (constant twiddles).
// A: stages 4-13 in contiguous 8192-chunks: radix-32 (stages 4-8 straight from
//    global, stride-8 comb) -> ONE LDS transpose -> radix-32 (stages 9-13).
// B: stages 14-22 over 512-elem stride-8192 combs: radix-32 (14-18) -> ONE LDS
//    transpose -> 2x radix-16 (19-22).
//
// All twiddles in a radix group derive from ONE sincos via exact double-angle
// + constant rotations (16-entry cos/sin(pi*k/16) table, folded at compile time).
// v_sin/v_cos take REVOLUTIONS.

#define NBITS 22
#define RSQ2 0.70710678118654752440f

__device__ __forceinline__ float hsqrt(float x) { return __builtin_amdgcn_sqrtf(x); }

__device__ __forceinline__ void bf(float& e, float& o, float c, float s) {
    float rp = fmaf(c, o, e);
    float rm = fmaf(-c, o, e);
    float im = s * o;
    float im2 = im * im;
    e = hsqrt(fmaf(rp, rp, im2));
    o = hsqrt(fmaf(rm, rm, im2));
}
__device__ __forceinline__ void bf0(float& e, float& o) {   // twiddle (1,0)
    float a = e + o, b = e - o;
    e = fabsf(a); o = fabsf(b);
}
__device__ __forceinline__ void bfq(float& e, float& o) {   // twiddle (0,1)
    float h = hsqrt(fmaf(e, e, o * o));
    e = h; o = h;
}

// Rotation constants: KC[k]=cos(pi*k/16), KS[k]=sin(pi*k/16) (offset k/32 rev).
__device__ __constant__ float KC[16] = {
    1.f, 0.980785280f, 0.923879533f, 0.831469612f, 0.707106781f, 0.555570233f,
    0.382683432f, 0.195090322f, 0.f, -0.195090322f, -0.382683432f, -0.555570233f,
    -0.707106781f, -0.831469612f, -0.923879533f, -0.980785280f };
__device__ __constant__ float KS[16] = {
    0.f, 0.195090322f, 0.382683432f, 0.555570233f, 0.707106781f, 0.831469612f,
    0.923879533f, 0.980785280f, 1.f, 0.980785280f, 0.923879533f, 0.831469612f,
    0.707106781f, 0.555570233f, 0.382683432f, 0.195090322f };

// radix-2^L (L<=5) on v[0..2^L), elements at p = P0 + j*H.
// (c,s) = cos/sin of r_base = P0 / (2^L * H) revolutions (LAST sub-stage base).
// Sub-stage a (pair dist 2^a in j): base angle r_base*2^(L-1-a) (double-angle),
// offset d/2^(a+1) rev = rotation table index d<<(4-a).
template <int L>
__device__ __forceinline__ void radixN(float* v, float c, float s) {
    float ca[L], sa[L];
    ca[L - 1] = c; sa[L - 1] = s;
#pragma unroll
    for (int a = L - 1; a > 0; --a) {
        ca[a - 1] = fmaf(-2.f * sa[a], sa[a], 1.f);
        sa[a - 1] = 2.f * sa[a] * ca[a];
    }
#pragma unroll
    for (int a = 0; a < L; ++a) {
        const int half = 1 << a;
#pragma unroll
        for (int d = 0; d < half; ++d) {
            const int k = d << (4 - a);
            float cd = fmaf(ca[a], KC[k], -sa[a] * KS[k]);
            float sd = fmaf(sa[a], KC[k],  ca[a] * KS[k]);
#pragma unroll
            for (int g = d; g < (1 << L); g += 2 * half)
                bf(v[g], v[g + half], cd, sd);
        }
    }
}

// stages 1..3 (twiddles all constant)
__device__ __forceinline__ void radix8z(float v[8]) {
    bf0(v[0], v[1]); bf0(v[2], v[3]); bf0(v[4], v[5]); bf0(v[6], v[7]);
    bf0(v[0], v[2]); bf0(v[4], v[6]);
    bfq(v[1], v[3]); bfq(v[5], v[7]);
    bf0(v[0], v[4]);
    bf(v[1], v[5], RSQ2, RSQ2);
    bfq(v[2], v[6]);
    bf(v[3], v[7], -RSQ2, RSQ2);
}

// ---------------- Kernel P: bitrev permute + stages 1..3 ----------------
// p = hi11*2048 + lo11; brev22(p) = brev11(lo11)*2048 + brev11(hi11).
__global__ __launch_bounds__(256, 8) void fft_perm(const float* __restrict__ x,
                                                   float* __restrict__ y) {
    __shared__ float lds[64 * 65];
    const unsigned tid = threadIdx.x;
    const unsigned tx = tid & 63, g = tid >> 6;
    const unsigned C0 = (blockIdx.x & 31) * 64;
    const unsigned B0 = (blockIdx.x >> 5) * 64;

#pragma unroll
    for (int k = 0; k < 16; ++k) {
        unsigned r = g * 16 + k;
        unsigned a = __brev(C0 + r) >> (32 - 11);
        lds[r * 65 + tx] = x[a * 2048u + B0 + tx];
    }
    __syncthreads();

    float v[8];
#pragma unroll
    for (int q = 0; q < 2; ++q) {
        unsigned task = tid + 256u * q;
        unsigned c = task >> 3, grp = task & 7;
#pragma unroll
        for (int j = 0; j < 8; ++j) v[j] = lds[(grp * 8 + j) * 65 + c];
        radix8z(v);
        unsigned pr = __brev(B0 + c) >> (32 - 11);
        float* dst = y + pr * 2048u + C0 + grp * 8;
        *(float4*)(dst)     = make_float4(v[0], v[1], v[2], v[3]);
        *(float4*)(dst + 4) = make_float4(v[4], v[5], v[6], v[7]);
    }
}

// ---------------- Kernel A: stages 4..13 ----------------
// LDS pad: addr(q) = q + (q>>5). Phase-1 writes (q = lo+8j+256hi, lanes vary
// lo,hi) and phase-2 reads (q = t+256j, lanes vary t) are both <=2-way.
__global__ __launch_bounds__(256, 4) void fft_low(float* __restrict__ y) {
    __shared__ float lds[8448];                   // 8191 + 255 + 1, padded
    const unsigned t = threadIdx.x;               // 0..255
    const unsigned base = blockIdx.x * 8192;
    const unsigned lo = t & 7, hi = t >> 3;       // hi 0..31
    float v[32];

    // phase 1: stages 4..8 on {lo + 8j + 256hi}, straight from global
    {
        const float* src = y + base + lo + 256u * hi;
#pragma unroll
        for (int j = 0; j < 32; ++j) v[j] = src[8 * j];
        float r = (float)lo * (1.f / 256.f);      // r_base = P0/(32*8)
        radixN<5>(v, __builtin_amdgcn_cosf(r), __builtin_amdgcn_sinf(r));
#pragma unroll
        for (int j = 0; j < 32; ++j) {
            unsigned q = lo + 8u * j + 256u * hi;
            lds[q + (q >> 5)] = v[j];
        }
    }
    __syncthreads();

    // phase 2: stages 9..13 on {t + 256j}, store coalesced
    {
#pragma unroll
        for (int j = 0; j < 32; ++j) {
            unsigned q = t + 256u * j;
            v[j] = lds[q + (q >> 5)];
        }
        float r = (float)t * (1.f / 8192.f);      // r_base = P0/(32*256)
        radixN<5>(v, __builtin_amdgcn_cosf(r), __builtin_amdgcn_sinf(r));
        float* dst = y + base + t;
#pragma unroll
        for (int j = 0; j < 32; ++j) dst[256u * j] = v[j];
    }
}

// ---------------- Kernel B: stages 14..22 ----------------
// 16 lows x 512 t (stride 8192). LDS addr(t,li) = t*17 + (t>>5) + li:
// phase-1 writes (t=32u5+j) and phase-2 reads (t=t0+32j) both <=2-way.
__global__ __launch_bounds__(256, 4) void fft_high(float* __restrict__ y) {
    __shared__ float lds[512 * 17 + 32];
    const unsigned tt = threadIdx.x;
    const unsigned li = tt & 15, u5 = tt >> 4;    // u5 0..15
    const unsigned low = blockIdx.x * 16 + li;
    float v[32];

    // phase 1: stages 14..18 on t = 32*u5 + j
    {
        const float* src = y + low;
#pragma unroll
        for (int j = 0; j < 32; ++j) v[j] = src[8192u * (32u * u5 + j)];
        float r = (float)low * (1.f / 262144.f);  // r_base = low/(32*8192)
        radixN<5>(v, __builtin_amdgcn_cosf(r), __builtin_amdgcn_sinf(r));
#pragma unroll
        for (int j = 0; j < 32; ++j) {
            unsigned trow = 32u * u5 + j;
            lds[trow * 17 + (trow >> 5) + li] = v[j];
        }
    }
    __syncthreads();

    // phase 2: stages 19..22, two radix-16 groups t0 = 2*u5 + b, t = t0 + 32j
#pragma unroll
    for (int b = 0; b < 2; ++b) {
        const unsigned t0 = 2u * u5 + b;
        float* w = v + 16 * b;
#pragma unroll
        for (int j = 0; j < 16; ++j) {
            unsigned trow = t0 + 32u * j;
            w[j] = lds[trow * 17 + (trow >> 5) + li];
        }
        float r = ((float)low + 8192.f * (float)t0) * (1.f / 4194304.f);
        radixN<4>(w, __builtin_amdgcn_cosf(r), __builtin_amdgcn_sinf(r));
#pragma unroll
        for (int j = 0; j < 16; ++j)
            y[low + 8192u * (t0 + 32u * j)] = w[j];
    }
}

extern "C" void kernel_launch(void* const* d_in, const int* in_sizes, int n_in,
                              void* d_out, int out_size, void* d_ws, size_t ws_size,
                              hipStream_t stream) {
    const float* x = (const float*)d_in[0];
    float* out = (float*)d_out;

    fft_perm<<<dim3(1024), dim3(256), 0, stream>>>(x, out);
    fft_low<<<dim3(512), dim3(256), 0, stream>>>(out);
    fft_high<<<dim3(512), dim3(256), 0, stream>>>(out);
}